// Round 3
// baseline (642.153 us; speedup 1.0000x reference)
//
#include <hip/hip_runtime.h>
#include <hip/hip_fp16.h>

#define NB 32
#define NL 512
#define NC 256

// ---------------------------------------------------------------------------
// Kernel 1: xc = x + conv_e + conv_p  (B,L,C)  +  rowdot rd[b,l] = sum_c xc*Wproj
// 4 rows per block (256 threads = 4 waves, one wave per row, lane covers 4 c's)
// ---------------------------------------------------------------------------
__global__ __launch_bounds__(256) void k_xc(
    const float* __restrict__ x,
    const float* __restrict__ energ,
    const float* __restrict__ pitch,
    const float* __restrict__ We, const float* __restrict__ be,
    const float* __restrict__ Wp, const float* __restrict__ bp,
    const float* __restrict__ Wproj,
    float* __restrict__ xc, float* __restrict__ rd)
{
    int blk = blockIdx.x;
    int b = blk >> 7;                       // 128 blocks per batch (L/4)
    int l = ((blk & 127) << 2) + (threadIdx.x >> 6);
    int lane = threadIdx.x & 63;
    int c0 = lane << 2;
    int rowoff = b * NL + l;

    float em1 = (l > 0)      ? energ[rowoff - 1] : 0.f;
    float e0  =                energ[rowoff];
    float ep1 = (l < NL - 1) ? energ[rowoff + 1] : 0.f;
    float pm1 = (l > 0)      ? pitch[rowoff - 1] : 0.f;
    float p0  =                pitch[rowoff];
    float pp1 = (l < NL - 1) ? pitch[rowoff + 1] : 0.f;

    float4 xv = *(const float4*)(x + (size_t)rowoff * NC + c0);
    float4 pw = *(const float4*)(Wproj + c0);
    const float* xvp = (const float*)&xv;
    const float* pwp = (const float*)&pw;
    float o[4];
    float dot = 0.f;
#pragma unroll
    for (int j = 0; j < 4; ++j) {
        int c = c0 + j;
        float conv = We[c*3+0]*em1 + We[c*3+1]*e0 + We[c*3+2]*ep1 + be[c]
                   + Wp[c*3+0]*pm1 + Wp[c*3+1]*p0 + Wp[c*3+2]*pp1 + bp[c];
        float v = xvp[j] + conv;
        o[j] = v;
        dot += v * pwp[j];
    }
    *(float4*)(xc + (size_t)rowoff * NC + c0) = *(float4*)o;
#pragma unroll
    for (int off = 32; off > 0; off >>= 1) dot += __shfl_down(dot, off, 64);
    if (lane == 0) rd[rowoff] = dot;
}

// ---------------------------------------------------------------------------
// Kernel 2: per-batch duration scan -> means; ranges via reduced conv weights.
// pw_k = sum_c Wd[c,k]*Wproj[c]  (computed per block, cheap)
// ---------------------------------------------------------------------------
__global__ __launch_bounds__(512) void k_ranges(
    const float* __restrict__ df, const int* __restrict__ di,
    const int* __restrict__ ilen,
    const float* __restrict__ Wd, const float* __restrict__ bd,
    const float* __restrict__ Wproj, const float* __restrict__ bproj,
    const float* __restrict__ rd,
    float* __restrict__ meanO, float* __restrict__ invrO, float* __restrict__ coefO)
{
    __shared__ float red[256];
    __shared__ float pwS[4];
    __shared__ int sbuf[2][NL];
    int b = blockIdx.x;
    int l = threadIdx.x;

    float v0 = 0.f, v1 = 0.f, v2 = 0.f, v3 = 0.f;
    if (l < 256) {
        float pw = Wproj[l];
        v0 = Wd[l*3+0] * pw;
        v1 = Wd[l*3+1] * pw;
        v2 = Wd[l*3+2] * pw;
        v3 = bd[l] * pw;
    }
    float vals[4] = {v0, v1, v2, v3};
#pragma unroll
    for (int q = 0; q < 4; ++q) {
        __syncthreads();
        if (l < 256) red[l] = vals[q];
        __syncthreads();
        for (int off = 128; off > 0; off >>= 1) {
            if (l < off) red[l] += red[l + off];
            __syncthreads();
        }
        if (l == 0) pwS[q] = red[0];
    }

    // inclusive scan of durations (Hillis-Steele, ping-pong)
    int d = di[b*NL + l];
    sbuf[0][l] = d;
    __syncthreads();
    int cur = 0;
    for (int off = 1; off < NL; off <<= 1) {
        int v = sbuf[cur][l];
        if (l >= off) v += sbuf[cur][l - off];
        sbuf[cur^1][l] = v;
        __syncthreads();
        cur ^= 1;
    }
    int incl = sbuf[cur][l];
    float mean = (float)incl - 0.5f * (float)d;   // excl + 0.5*d

    float fm1 = (l > 0)      ? df[b*NL + l - 1] : 0.f;
    float f0  =                df[b*NL + l];
    float fp1 = (l < NL - 1) ? df[b*NL + l + 1] : 0.f;
    float rin = rd[b*NL + l] + pwS[0]*fm1 + pwS[1]*f0 + pwS[2]*fp1
              + pwS[3] + bproj[0];
    float rng = (rin > 20.f) ? rin : log1pf(expf(rin));   // softplus
    bool pad = (l >= ilen[b]);
    float invr = 1.f / rng;
    meanO[b*NL + l] = mean;
    invrO[b*NL + l] = pad ? 1.f : invr;
    coefO[b*NL + l] = pad ? 0.f : 0.3989422804014327f * invr; // 1/(r*sqrt(2pi))
}

// ---------------------------------------------------------------------------
// Kernel 3: per (b, 32-wide t-tile):
//   phase 1: fp32 probs (recomputable) -> per-column denominator
//   phase 2: recompute fp32 probs, exact fp32 weights -> global; fp16 weights -> LDS
//   phase 3: out[t,c] = sum_l w[l,t] * xc[l,c]   (fp32 VALU GEMM)
// All prob math stays fp32 end-to-end (the fp16-probs flush was round-1's bug);
// fp16 is applied only to normalized weights as GEMM input (<=2^-11 rel err).
// ---------------------------------------------------------------------------
__global__ __launch_bounds__(256) void k_main(
    const float* __restrict__ xc,
    const float* __restrict__ meanA,
    const float* __restrict__ invrA,
    const float* __restrict__ coefA,
    float* __restrict__ outX, float* __restrict__ outW, int T)
{
    __shared__ __align__(16) __half hsw[NL][32];   // 32 KB: normalized weights (GEMM input only)
    __shared__ float red[8][32];
    __shared__ float dinv[32];

    int b = blockIdx.y;
    int t0 = blockIdx.x << 5;
    int tid = threadIdx.x;
    int tcol = tid & 31;
    int lbase = tid >> 5;

    const float* meanB = meanA + b * NL;
    const float* invrB = invrA + b * NL;
    const float* coefB = coefA + b * NL;
    float frame = (float)(t0 + tcol) + 0.5f;

    // phase 1: fp32 probs, fused per-column partial sums (no storage)
    float partial = 0.f;
#pragma unroll 4
    for (int i = 0; i < 64; ++i) {
        int l = lbase + (i << 3);
        float z = (frame - meanB[l]) * invrB[l];
        float z2 = z * z;
        // z2 >= 450: fp32 exp underflows to exact 0 even with max coef — bit-exact skip
        float p = (z2 < 450.f) ? coefB[l] * __expf(-0.5f * z2) : 0.f;
        partial += p;
    }
    red[lbase][tcol] = partial;
    __syncthreads();
    if (tid < 32) {
        float s = 0.f;
#pragma unroll
        for (int g = 0; g < 8; ++g) s += red[g][tid];
        dinv[tid] = 1.f / (s + 1e-20f);
    }
    __syncthreads();

    // phase 2: recompute fp32 probs (identical expr -> identical bits),
    // exact fp32 weights to global, fp16 normalized weights to LDS
    float dv = dinv[tcol];
    bool tok = (t0 + tcol) < T;
    float* wrow = outW + (size_t)b * NL * T + (t0 + tcol);
#pragma unroll 4
    for (int i = 0; i < 64; ++i) {
        int l = lbase + (i << 3);
        float z = (frame - meanB[l]) * invrB[l];
        float z2 = z * z;
        float p = (z2 < 450.f) ? coefB[l] * __expf(-0.5f * z2) : 0.f;
        float wf = p * dv;
        hsw[l][tcol] = __float2half(wf);
        if (tok) wrow[(size_t)l * T] = wf;
    }
    __syncthreads();

    // phase 3: GEMM  out[t, c] = sum_l w[l][t] * xc[l][c]
    int lane = tid & 63;
    int tg = tid >> 6;                           // wave owns 8 t's
    const float* xcB = xc + (size_t)b * NL * NC + (lane << 2);
    float4 acc[8];
#pragma unroll
    for (int t = 0; t < 8; ++t) acc[t] = make_float4(0.f, 0.f, 0.f, 0.f);

    for (int l = 0; l < NL; ++l) {
        float4 xv = *(const float4*)(xcB + (size_t)l * NC);
        const __half2* wp = (const __half2*)&hsw[l][tg << 3];
        __half2 w0 = wp[0], w1 = wp[1], w2 = wp[2], w3 = wp[3];
        float2 g0 = __half22float2(w0);
        float2 g1 = __half22float2(w1);
        float2 g2 = __half22float2(w2);
        float2 g3 = __half22float2(w3);
        float wv[8] = {g0.x, g0.y, g1.x, g1.y, g2.x, g2.y, g3.x, g3.y};
#pragma unroll
        for (int t = 0; t < 8; ++t) {
            acc[t].x += wv[t] * xv.x;
            acc[t].y += wv[t] * xv.y;
            acc[t].z += wv[t] * xv.z;
            acc[t].w += wv[t] * xv.w;
        }
    }

    int trow0 = t0 + (tg << 3);
    float* outB = outX + (size_t)b * T * NC + (size_t)trow0 * NC + (lane << 2);
#pragma unroll
    for (int t = 0; t < 8; ++t) {
        if (trow0 + t < T)
            *(float4*)(outB + (size_t)t * NC) = acc[t];
    }
}

// ---------------------------------------------------------------------------
extern "C" void kernel_launch(void* const* d_in, const int* in_sizes, int n_in,
                              void* d_out, int out_size, void* d_ws, size_t ws_size,
                              hipStream_t stream)
{
    const float* x   = (const float*)d_in[0];
    const float* df  = (const float*)d_in[1];
    const float* en  = (const float*)d_in[2];
    const float* pi  = (const float*)d_in[3];
    const float* Wd  = (const float*)d_in[4];
    const float* bd  = (const float*)d_in[5];
    const float* We  = (const float*)d_in[6];
    const float* be  = (const float*)d_in[7];
    const float* Wp  = (const float*)d_in[8];
    const float* bp  = (const float*)d_in[9];
    const float* Wpr = (const float*)d_in[10];
    const float* bpr = (const float*)d_in[11];
    const int*   di  = (const int*)d_in[12];
    const int*   il  = (const int*)d_in[13];

    // out_size = B*T*C + B*L*T = B*(C+L)*T
    int T = out_size / (NB * (NC + NL));

    float* outX = (float*)d_out;
    float* outW = outX + (size_t)NB * T * NC;

    float* xcp   = (float*)d_ws;                  // B*L*C
    float* rdp   = xcp + (size_t)NB * NL * NC;    // B*L
    float* meanp = rdp + NB * NL;
    float* invrp = meanp + NB * NL;
    float* coefp = invrp + NB * NL;

    hipLaunchKernelGGL(k_xc, dim3(NB * NL / 4), dim3(256), 0, stream,
                       x, en, pi, We, be, Wp, bp, Wpr, xcp, rdp);
    hipLaunchKernelGGL(k_ranges, dim3(NB), dim3(512), 0, stream,
                       df, di, il, Wd, bd, Wpr, bpr, rdp, meanp, invrp, coefp);
    hipLaunchKernelGGL(k_main, dim3((T + 31) / 32, NB), dim3(256), 0, stream,
                       xcp, meanp, invrp, coefp, outX, outW, T);
}

// Round 4
// 452.138 us; speedup vs baseline: 1.4203x; 1.4203x over previous
//
#include <hip/hip_runtime.h>

#define NB 32
#define NL 512
#define NC 256

typedef __attribute__((ext_vector_type(8))) short short8v;   // 8 bf16 (4 VGPRs)
typedef __attribute__((ext_vector_type(4))) float f32x4;     // MFMA C/D

__device__ __forceinline__ unsigned short f2bf(float x) {
    unsigned int u = __float_as_uint(x);
    unsigned int r = (u + 0x7FFFu + ((u >> 16) & 1u)) >> 16;  // RNE
    return (unsigned short)r;
}

// ---------------------------------------------------------------------------
// Kernel 1: xc = x + conv_e + conv_p; emit bf16 TRANSPOSED xcT[b][c][l] (MFMA
// B-operand wants l-consecutive) + rowdot rd[b,l] = sum_c xc*Wproj (fp32).
// 4 rows per block (256 thr = 4 waves, wave per l-row, lane covers 4 c's).
// ---------------------------------------------------------------------------
__global__ __launch_bounds__(256) void k_xc(
    const float* __restrict__ x,
    const float* __restrict__ energ,
    const float* __restrict__ pitch,
    const float* __restrict__ We, const float* __restrict__ be,
    const float* __restrict__ Wp, const float* __restrict__ bp,
    const float* __restrict__ Wproj,
    unsigned short* __restrict__ xcT, float* __restrict__ rd)
{
    int blk = blockIdx.x;
    int b = blk >> 7;                       // 128 blocks per batch (L/4)
    int l = ((blk & 127) << 2) + (threadIdx.x >> 6);
    int lane = threadIdx.x & 63;
    int c0 = lane << 2;
    int rowoff = b * NL + l;

    float em1 = (l > 0)      ? energ[rowoff - 1] : 0.f;
    float e0  =                energ[rowoff];
    float ep1 = (l < NL - 1) ? energ[rowoff + 1] : 0.f;
    float pm1 = (l > 0)      ? pitch[rowoff - 1] : 0.f;
    float p0  =                pitch[rowoff];
    float pp1 = (l < NL - 1) ? pitch[rowoff + 1] : 0.f;

    float4 xv = *(const float4*)(x + (size_t)rowoff * NC + c0);
    float4 pw = *(const float4*)(Wproj + c0);
    const float* xvp = (const float*)&xv;
    const float* pwp = (const float*)&pw;
    float dot = 0.f;
    unsigned short* base = xcT + (size_t)b * NC * NL + (size_t)c0 * NL + l;
#pragma unroll
    for (int j = 0; j < 4; ++j) {
        int c = c0 + j;
        float conv = We[c*3+0]*em1 + We[c*3+1]*e0 + We[c*3+2]*ep1 + be[c]
                   + Wp[c*3+0]*pm1 + Wp[c*3+1]*p0 + Wp[c*3+2]*pp1 + bp[c];
        float v = xvp[j] + conv;
        base[(size_t)j * NL] = f2bf(v);     // scattered u16 (stride 1 KB) — L2 absorbs
        dot += v * pwp[j];
    }
#pragma unroll
    for (int off = 32; off > 0; off >>= 1) dot += __shfl_down(dot, off, 64);
    if (lane == 0) rd[rowoff] = dot;
}

// ---------------------------------------------------------------------------
// Kernel 2: per-batch duration scan -> means; ranges via reduced conv weights.
// ---------------------------------------------------------------------------
__global__ __launch_bounds__(512) void k_ranges(
    const float* __restrict__ df, const int* __restrict__ di,
    const int* __restrict__ ilen,
    const float* __restrict__ Wd, const float* __restrict__ bd,
    const float* __restrict__ Wproj, const float* __restrict__ bproj,
    const float* __restrict__ rd,
    float* __restrict__ meanO, float* __restrict__ invrO, float* __restrict__ coefO)
{
    __shared__ float red[256];
    __shared__ float pwS[4];
    __shared__ int sbuf[2][NL];
    int b = blockIdx.x;
    int l = threadIdx.x;

    float v0 = 0.f, v1 = 0.f, v2 = 0.f, v3 = 0.f;
    if (l < 256) {
        float pw = Wproj[l];
        v0 = Wd[l*3+0] * pw;
        v1 = Wd[l*3+1] * pw;
        v2 = Wd[l*3+2] * pw;
        v3 = bd[l] * pw;
    }
    float vals[4] = {v0, v1, v2, v3};
#pragma unroll
    for (int q = 0; q < 4; ++q) {
        __syncthreads();
        if (l < 256) red[l] = vals[q];
        __syncthreads();
        for (int off = 128; off > 0; off >>= 1) {
            if (l < off) red[l] += red[l + off];
            __syncthreads();
        }
        if (l == 0) pwS[q] = red[0];
    }

    int d = di[b*NL + l];
    sbuf[0][l] = d;
    __syncthreads();
    int cur = 0;
    for (int off = 1; off < NL; off <<= 1) {
        int v = sbuf[cur][l];
        if (l >= off) v += sbuf[cur][l - off];
        sbuf[cur^1][l] = v;
        __syncthreads();
        cur ^= 1;
    }
    int incl = sbuf[cur][l];
    float mean = (float)incl - 0.5f * (float)d;   // exclusive cumsum + d/2

    float fm1 = (l > 0)      ? df[b*NL + l - 1] : 0.f;
    float f0  =                df[b*NL + l];
    float fp1 = (l < NL - 1) ? df[b*NL + l + 1] : 0.f;
    float rin = rd[b*NL + l] + pwS[0]*fm1 + pwS[1]*f0 + pwS[2]*fp1
              + pwS[3] + bproj[0];
    float rng = (rin > 20.f) ? rin : log1pf(expf(rin));   // softplus
    bool pad = (l >= ilen[b]);
    float invr = 1.f / rng;
    meanO[b*NL + l] = mean;
    invrO[b*NL + l] = pad ? 1.f : invr;
    coefO[b*NL + l] = pad ? 0.f : 0.3989422804014327f * invr; // 1/(r*sqrt(2pi))
}

// ---------------------------------------------------------------------------
// Kernel 3: per (b, 32-wide t-tile):
//   phase 1: fp32 probs -> per-column denominator (no storage)
//   phase 2: recompute fp32 probs (bit-identical), exact fp32 weights -> global;
//            bf16 weights -> LDS as wT[t][l] with XOR swizzle (byte ^= (t&7)<<4)
//   phase 3: MFMA 16x16x32 bf16: out[t,c] = sum_l w[t,l] * xcT[c,l]
//     A-frag: lane holds wT[t = lane&15 (+16*mt)][l0 + (lane>>4)*8 + j]
//     B-frag: lane holds xcT[c = lane&15 (+16*nt +64*wave)][l0 + (lane>>4)*8 + j]
//     D: col(c)=lane&15, row(t)=(lane>>4)*4+reg  [m89-verified]
// ---------------------------------------------------------------------------
__global__ __launch_bounds__(256) void k_main(
    const unsigned short* __restrict__ xcT,
    const float* __restrict__ meanA,
    const float* __restrict__ invrA,
    const float* __restrict__ coefA,
    float* __restrict__ outX, float* __restrict__ outW, int T)
{
    __shared__ __align__(16) unsigned short wT[32 * NL];  // 32 KB, swizzled
    __shared__ float red[8][32];
    __shared__ float dinv[32];

    int b = blockIdx.y;
    int t0 = blockIdx.x << 5;
    int tid = threadIdx.x;
    int tcol = tid & 31;
    int lbase = tid >> 5;

    const float* meanB = meanA + b * NL;
    const float* invrB = invrA + b * NL;
    const float* coefB = coefA + b * NL;
    float frame = (float)(t0 + tcol) + 0.5f;

    // phase 1: fp32 probs, fused per-column partial sums
    float partial = 0.f;
#pragma unroll 4
    for (int i = 0; i < 64; ++i) {
        int l = lbase + (i << 3);
        float z = (frame - meanB[l]) * invrB[l];
        float z2 = z * z;
        float p = (z2 < 450.f) ? coefB[l] * __expf(-0.5f * z2) : 0.f;
        partial += p;
    }
    red[lbase][tcol] = partial;
    __syncthreads();
    if (tid < 32) {
        float s = 0.f;
#pragma unroll
        for (int g = 0; g < 8; ++g) s += red[g][tid];
        dinv[tid] = 1.f / (s + 1e-20f);
    }
    __syncthreads();

    // phase 2: recompute probs, fp32 weights -> global, bf16 -> swizzled LDS
    float dv = dinv[tcol];
    bool tok = (t0 + tcol) < T;
    float* wrow = outW + (size_t)b * NL * T + (t0 + tcol);
    char* wbase = (char*)wT;
    int sw = (tcol & 7) << 4;
    int trowoff = tcol << 10;                 // t*1024 bytes
#pragma unroll 4
    for (int i = 0; i < 64; ++i) {
        int l = lbase + (i << 3);
        float z = (frame - meanB[l]) * invrB[l];
        float z2 = z * z;
        float p = (z2 < 450.f) ? coefB[l] * __expf(-0.5f * z2) : 0.f;
        float wf = p * dv;
        *(unsigned short*)(wbase + ((trowoff + l * 2) ^ sw)) = f2bf(wf);
        if (tok) wrow[(size_t)l * T] = wf;
    }
    __syncthreads();

    // phase 3: MFMA GEMM. 4 waves; wave wv owns c in [wv*64, wv*64+64).
    int lane = tid & 63;
    int wv = tid >> 6;
    int g = lane >> 4;
    int m = lane & 15;

    f32x4 acc[2][4];
#pragma unroll
    for (int mt = 0; mt < 2; ++mt)
#pragma unroll
        for (int nt = 0; nt < 4; ++nt) acc[mt][nt] = (f32x4){0.f, 0.f, 0.f, 0.f};

    const unsigned short* xb = xcT + (size_t)b * NC * NL + (size_t)g * 8;
    size_t bofs[4];
#pragma unroll
    for (int nt = 0; nt < 4; ++nt)
        bofs[nt] = (size_t)(wv * 64 + nt * 16 + m) * NL;

    int asw = (m & 7) << 4;                   // (16+m)&7 == m&7
    int a0off = (m << 10) + (g << 4);
    int a1off = ((16 + m) << 10) + (g << 4);

    for (int l0 = 0; l0 < NL; l0 += 32) {
        short8v a0 = *(const short8v*)(wbase + ((a0off + l0 * 2) ^ asw));
        short8v a1 = *(const short8v*)(wbase + ((a1off + l0 * 2) ^ asw));
#pragma unroll
        for (int nt = 0; nt < 4; ++nt) {
            short8v bf = *(const short8v*)(xb + bofs[nt] + l0);
            acc[0][nt] = __builtin_amdgcn_mfma_f32_16x16x32_bf16(a0, bf, acc[0][nt], 0, 0, 0);
            acc[1][nt] = __builtin_amdgcn_mfma_f32_16x16x32_bf16(a1, bf, acc[1][nt], 0, 0, 0);
        }
    }

    // epilogue: D row(t) = (lane>>4)*4 + r, col(c) = lane&15
    float* outB = outX + (size_t)b * T * NC + (size_t)(wv * 64 + m);
#pragma unroll
    for (int mt = 0; mt < 2; ++mt) {
#pragma unroll
        for (int r = 0; r < 4; ++r) {
            int t = t0 + mt * 16 + g * 4 + r;
            if (t < T) {
#pragma unroll
                for (int nt = 0; nt < 4; ++nt)
                    outB[(size_t)t * NC + nt * 16] = acc[mt][nt][r];
            }
        }
    }
}

// ---------------------------------------------------------------------------
extern "C" void kernel_launch(void* const* d_in, const int* in_sizes, int n_in,
                              void* d_out, int out_size, void* d_ws, size_t ws_size,
                              hipStream_t stream)
{
    const float* x   = (const float*)d_in[0];
    const float* df  = (const float*)d_in[1];
    const float* en  = (const float*)d_in[2];
    const float* pi  = (const float*)d_in[3];
    const float* Wd  = (const float*)d_in[4];
    const float* bd  = (const float*)d_in[5];
    const float* We  = (const float*)d_in[6];
    const float* be  = (const float*)d_in[7];
    const float* Wp  = (const float*)d_in[8];
    const float* bp  = (const float*)d_in[9];
    const float* Wpr = (const float*)d_in[10];
    const float* bpr = (const float*)d_in[11];
    const int*   di  = (const int*)d_in[12];
    const int*   il  = (const int*)d_in[13];

    // out_size = B*T*C + B*L*T = B*(C+L)*T
    int T = out_size / (NB * (NC + NL));

    float* outX = (float*)d_out;
    float* outW = outX + (size_t)NB * T * NC;

    float* rdp   = (float*)d_ws;                  // B*L
    float* meanp = rdp + NB * NL;
    float* invrp = meanp + NB * NL;
    float* coefp = invrp + NB * NL;
    unsigned short* xcT = (unsigned short*)(coefp + NB * NL);  // B*C*L bf16

    hipLaunchKernelGGL(k_xc, dim3(NB * NL / 4), dim3(256), 0, stream,
                       x, en, pi, We, be, Wp, bp, Wpr, xcT, rdp);
    hipLaunchKernelGGL(k_ranges, dim3(NB), dim3(512), 0, stream,
                       df, di, il, Wd, bd, Wpr, bpr, rdp, meanp, invrp, coefp);
    hipLaunchKernelGGL(k_main, dim3((T + 31) / 32, NB), dim3(256), 0, stream,
                       xcT, meanp, invrp, coefp, outX, outW, T);
}

// Round 5
// 332.684 us; speedup vs baseline: 1.9302x; 1.3591x over previous
//
#include <hip/hip_runtime.h>

#define NB 32
#define NL 512
#define NC 256

typedef __attribute__((ext_vector_type(8))) short short8v;   // 8 bf16
typedef __attribute__((ext_vector_type(4))) float f32x4;     // MFMA C/D

__device__ __forceinline__ unsigned short f2bf(float x) {
    unsigned int u = __float_as_uint(x);
    unsigned int r = (u + 0x7FFFu + ((u >> 16) & 1u)) >> 16;  // RNE
    return (unsigned short)r;
}

// ---------------------------------------------------------------------------
// k_xct: xc = x + conv_e + conv_p -> bf16 TILED transpose xcT[b][lt][c][32]
// block = (lt, b); thread per c. x reads coalesced (1KB/instr); stores cover
// a contiguous 16KB tile per block (L2 merges the 16B/lane pieces).
// ---------------------------------------------------------------------------
__global__ __launch_bounds__(256) void k_xct(
    const float* __restrict__ x,
    const float* __restrict__ energ, const float* __restrict__ pitch,
    const float* __restrict__ We, const float* __restrict__ be,
    const float* __restrict__ Wp, const float* __restrict__ bp,
    unsigned short* __restrict__ xcT)
{
    __shared__ float se[34], sp[34];
    int lt = blockIdx.x, b = blockIdx.y;
    int c = threadIdx.x;
    int l0 = lt * 32;
    if (c < 34) {
        int gl = l0 - 1 + c;
        bool ok = (gl >= 0) && (gl < NL);
        se[c] = ok ? energ[b*NL + gl] : 0.f;
        sp[c] = ok ? pitch[b*NL + gl] : 0.f;
    }
    __syncthreads();
    float we0 = We[c*3], we1 = We[c*3+1], we2 = We[c*3+2];
    float wp0 = Wp[c*3], wp1 = Wp[c*3+1], wp2 = Wp[c*3+2];
    float bb = be[c] + bp[c];
    const float* xb = x + ((size_t)b*NL + l0)*NC + c;
    unsigned int w32[16];
#pragma unroll
    for (int l = 0; l < 32; ++l) {
        float conv = we0*se[l] + we1*se[l+1] + we2*se[l+2]
                   + wp0*sp[l] + wp1*sp[l+1] + wp2*sp[l+2] + bb;
        float v = xb[(size_t)l*NC] + conv;
        unsigned int bits = f2bf(v);
        if (l & 1) w32[l>>1] |= bits << 16;
        else       w32[l>>1]  = bits;
    }
    uint4* dst = (uint4*)(xcT + ((size_t)(b*16 + lt)*NC + c)*32);
    const uint4* src = (const uint4*)w32;
#pragma unroll
    for (int k = 0; k < 4; ++k) dst[k] = src[k];
}

// ---------------------------------------------------------------------------
// k_rdx: rd[b,l] = sum_c x[b,l,c]*Wproj[c]  (x-only; conv terms folded into
// k_ranges via per-tap reduced weights). Wave per l-row.
// ---------------------------------------------------------------------------
__global__ __launch_bounds__(256) void k_rdx(
    const float* __restrict__ x, const float* __restrict__ Wproj,
    float* __restrict__ rd)
{
    int blk = blockIdx.x;
    int b = blk >> 7;
    int l = ((blk & 127) << 2) + (threadIdx.x >> 6);
    int lane = threadIdx.x & 63;
    int c0 = lane << 2;
    float4 xv = *(const float4*)(x + ((size_t)(b*NL + l))*NC + c0);
    float4 pw = *(const float4*)(Wproj + c0);
    float dot = xv.x*pw.x + xv.y*pw.y + xv.z*pw.z + xv.w*pw.w;
#pragma unroll
    for (int off = 32; off > 0; off >>= 1) dot += __shfl_down(dot, off, 64);
    if (lane == 0) rd[b*NL + l] = dot;
}

// ---------------------------------------------------------------------------
// k_ranges: duration scan -> means; ranges = softplus(rd_x + sum of per-tap
// reduced conv projections). 10 reduced scalars: pwD[3], pwE[3], pwP[3], bias.
// ---------------------------------------------------------------------------
__global__ __launch_bounds__(512) void k_ranges(
    const float* __restrict__ df, const float* __restrict__ energ,
    const float* __restrict__ pitch, const int* __restrict__ di,
    const int* __restrict__ ilen,
    const float* __restrict__ Wd, const float* __restrict__ bd,
    const float* __restrict__ We, const float* __restrict__ be,
    const float* __restrict__ Wp, const float* __restrict__ bp,
    const float* __restrict__ Wproj, const float* __restrict__ bproj,
    const float* __restrict__ rd,
    float* __restrict__ meanO, float* __restrict__ invrO, float* __restrict__ coefO)
{
    __shared__ float red[256];
    __shared__ float pwS[10];
    __shared__ int sbuf[2][NL];
    int b = blockIdx.x;
    int l = threadIdx.x;
    float vals[10];
#pragma unroll
    for (int q = 0; q < 10; ++q) vals[q] = 0.f;
    if (l < 256) {
        float w = Wproj[l];
        vals[0] = Wd[l*3]*w; vals[1] = Wd[l*3+1]*w; vals[2] = Wd[l*3+2]*w;
        vals[3] = We[l*3]*w; vals[4] = We[l*3+1]*w; vals[5] = We[l*3+2]*w;
        vals[6] = Wp[l*3]*w; vals[7] = Wp[l*3+1]*w; vals[8] = Wp[l*3+2]*w;
        vals[9] = (bd[l] + be[l] + bp[l])*w;
    }
#pragma unroll
    for (int q = 0; q < 10; ++q) {
        __syncthreads();
        if (l < 256) red[l] = vals[q];
        __syncthreads();
        for (int off = 128; off > 0; off >>= 1) {
            if (l < off) red[l] += red[l + off];
            __syncthreads();
        }
        if (l == 0) pwS[q] = red[0];
    }

    int d = di[b*NL + l];
    sbuf[0][l] = d;
    __syncthreads();
    int cur = 0;
    for (int off = 1; off < NL; off <<= 1) {
        int v = sbuf[cur][l];
        if (l >= off) v += sbuf[cur][l - off];
        sbuf[cur^1][l] = v;
        __syncthreads();
        cur ^= 1;
    }
    int incl = sbuf[cur][l];
    float mean = (float)incl - 0.5f*(float)d;

    int ro = b*NL + l;
    float fm1 = (l > 0)      ? df[ro-1]    : 0.f;
    float f0  =                df[ro];
    float fp1 = (l < NL-1)   ? df[ro+1]    : 0.f;
    float em1 = (l > 0)      ? energ[ro-1] : 0.f;
    float e0  =                energ[ro];
    float ep1 = (l < NL-1)   ? energ[ro+1] : 0.f;
    float pm1 = (l > 0)      ? pitch[ro-1] : 0.f;
    float p0  =                pitch[ro];
    float pp1 = (l < NL-1)   ? pitch[ro+1] : 0.f;
    float rin = rd[ro]
              + pwS[0]*fm1 + pwS[1]*f0 + pwS[2]*fp1
              + pwS[3]*em1 + pwS[4]*e0 + pwS[5]*ep1
              + pwS[6]*pm1 + pwS[7]*p0 + pwS[8]*pp1
              + pwS[9] + bproj[0];
    float rng = (rin > 20.f) ? rin : log1pf(expf(rin));   // softplus
    bool pad = (l >= ilen[b]);
    float invr = 1.f / rng;
    meanO[ro] = mean;
    invrO[ro] = pad ? 1.f : invr;
    coefO[ro] = pad ? 0.f : 0.3989422804014327f * invr;   // 1/(r*sqrt(2pi))
}

// ---------------------------------------------------------------------------
// k_denom: dinv[b,t] = 1/(sum_l p + 1e-20). block = (t-tile of 64, b);
// 4 l-partitions x 64 t-lanes, LDS reduce.
// ---------------------------------------------------------------------------
__global__ __launch_bounds__(256) void k_denom(
    const float* __restrict__ meanA, const float* __restrict__ invrA,
    const float* __restrict__ coefA, float* __restrict__ dinvA, int T)
{
    __shared__ float red[4][64];
    int b = blockIdx.y;
    int tl = threadIdx.x & 63;
    int part = threadIdx.x >> 6;
    int t = (blockIdx.x << 6) + tl;
    float fr = (float)t + 0.5f;
    const float* mB = meanA + b*NL + part*128;
    const float* iB = invrA + b*NL + part*128;
    const float* cB = coefA + b*NL + part*128;
    float s = 0.f;
#pragma unroll 4
    for (int i = 0; i < 128; ++i) {
        float z = (fr - mB[i]) * iB[i];
        float z2 = z*z;
        s += (z2 < 450.f) ? cB[i]*__expf(-0.5f*z2) : 0.f;
    }
    red[part][tl] = s;
    __syncthreads();
    if (threadIdx.x < 64) {
        float tot = red[0][threadIdx.x] + red[1][threadIdx.x]
                  + red[2][threadIdx.x] + red[3][threadIdx.x];
        int tt = (blockIdx.x << 6) + threadIdx.x;
        if (tt < T) dinvA[(size_t)b*T + tt] = 1.f / (tot + 1e-20f);
    }
}

// ---------------------------------------------------------------------------
// k_weights: outW[b,l,t] = p*dinv with fully t-contiguous coalesced stores.
// block = (l-tile of 32, b); 256 lanes sweep t in 256-wide chunks.
// ---------------------------------------------------------------------------
__global__ __launch_bounds__(256) void k_weights(
    const float* __restrict__ meanA, const float* __restrict__ invrA,
    const float* __restrict__ coefA, const float* __restrict__ dinvA,
    float* __restrict__ outW, int T)
{
    __shared__ float sm[32], si[32], sc[32];
    int lt = blockIdx.x, b = blockIdx.y;
    int l0 = lt*32;
    int tid = threadIdx.x;
    if (tid < 32) {
        sm[tid] = meanA[b*NL + l0 + tid];
        si[tid] = invrA[b*NL + l0 + tid];
        sc[tid] = coefA[b*NL + l0 + tid];
    }
    __syncthreads();
    int nch = (T + 255) >> 8;
    float* ow = outW + (size_t)b*NL*T + (size_t)l0*T;
    for (int ch = 0; ch < nch; ++ch) {
        int t = (ch << 8) + tid;
        bool tok = t < T;
        float dv = tok ? dinvA[(size_t)b*T + t] : 0.f;
        float fr = (float)t + 0.5f;
#pragma unroll
        for (int r = 0; r < 32; ++r) {
            float z = (fr - sm[r]) * si[r];
            float z2 = z*z;
            float p = (z2 < 450.f) ? sc[r]*__expf(-0.5f*z2) : 0.f;
            if (tok) ow[(size_t)r*T + t] = p * dv;
        }
    }
}

// ---------------------------------------------------------------------------
// k_gemm: per (b, 32-t tile): bf16 weights -> swizzled LDS (b128 writes) with
// per-32-l-chunk nonzero flags; MFMA 16x16x32 over flagged chunks only.
// ---------------------------------------------------------------------------
__global__ __launch_bounds__(256) void k_gemm(
    const unsigned short* __restrict__ xcT,
    const float* __restrict__ meanA, const float* __restrict__ invrA,
    const float* __restrict__ coefA, const float* __restrict__ dinvA,
    float* __restrict__ outX, int T)
{
    __shared__ __align__(16) unsigned short wT[32 * NL];  // 32 KB, swizzled
    __shared__ unsigned int fl[16];
    int b = blockIdx.y;
    int t0 = blockIdx.x << 5;
    int tid = threadIdx.x;
    int tcol = tid & 31;
    int lbase = tid >> 5;
    if (tid < 16) fl[tid] = 0;
    __syncthreads();

    int t = t0 + tcol;
    float dv = (t < T) ? dinvA[(size_t)b*T + t] : 0.f;
    float fr = (float)t + 0.5f;
    const float* mB = meanA + b*NL;
    const float* iB = invrA + b*NL;
    const float* cB = coefA + b*NL;
    char* wbase = (char*)wT;
    int sw = (tcol & 7) << 4;

    // phase A: 8 chunks of 8 consecutive l per thread -> one b128 LDS write each
#pragma unroll
    for (int i = 0; i < 8; ++i) {
        int ci = lbase + (i << 3);       // chunk index 0..63
        int lc = ci << 3;                // l0 of chunk
        const float4 m0  = *(const float4*)(mB + lc);
        const float4 m1  = *(const float4*)(mB + lc + 4);
        const float4 iv0 = *(const float4*)(iB + lc);
        const float4 iv1 = *(const float4*)(iB + lc + 4);
        const float4 cv0 = *(const float4*)(cB + lc);
        const float4 cv1 = *(const float4*)(cB + lc + 4);
        float mm[8] = {m0.x,m0.y,m0.z,m0.w,m1.x,m1.y,m1.z,m1.w};
        float ii[8] = {iv0.x,iv0.y,iv0.z,iv0.w,iv1.x,iv1.y,iv1.z,iv1.w};
        float cc[8] = {cv0.x,cv0.y,cv0.z,cv0.w,cv1.x,cv1.y,cv1.z,cv1.w};
        float w8[8];
        float sum = 0.f;
#pragma unroll
        for (int j = 0; j < 8; ++j) {
            float z = (fr - mm[j]) * ii[j];
            float z2 = z*z;
            float p = (z2 < 450.f) ? cc[j]*__expf(-0.5f*z2) : 0.f;
            float wv2 = p * dv;
            w8[j] = wv2;
            sum += wv2;
        }
        if (sum > 0.f) fl[ci >> 2] = 1u;           // benign race (same value)
        union { unsigned int u[4]; short8v v; } pk;
#pragma unroll
        for (int j = 0; j < 4; ++j)
            pk.u[j] = (unsigned int)f2bf(w8[2*j]) | ((unsigned int)f2bf(w8[2*j+1]) << 16);
        *(short8v*)(wbase + (((tcol << 10) + (ci << 4)) ^ sw)) = pk.v;
    }
    __syncthreads();

    // phase B: MFMA over flagged K-chunks. wave wvid owns c in [wvid*64, +64).
    int lane = tid & 63;
    int wvid = tid >> 6;
    int g = lane >> 4;
    int m = lane & 15;
    f32x4 acc[2][4];
#pragma unroll
    for (int mt = 0; mt < 2; ++mt)
#pragma unroll
        for (int nt = 0; nt < 4; ++nt) acc[mt][nt] = (f32x4){0.f,0.f,0.f,0.f};

    const unsigned short* xb = xcT + (size_t)b * 16 * 8192;   // [lt][c][32]
    int asw = (m & 7) << 4;

    for (int ks = 0; ks < 16; ++ks) {
        if (fl[ks] == 0u) continue;
        const unsigned short* xk = xb + ks*8192 + g*8;
        short8v a0 = *(const short8v*)(wbase + (((m << 10)      + ks*64 + (g << 4)) ^ asw));
        short8v a1 = *(const short8v*)(wbase + ((((16+m) << 10) + ks*64 + (g << 4)) ^ asw));
#pragma unroll
        for (int nt = 0; nt < 4; ++nt) {
            short8v bf = *(const short8v*)(xk + (size_t)(wvid*64 + nt*16 + m)*32);
            acc[0][nt] = __builtin_amdgcn_mfma_f32_16x16x32_bf16(a0, bf, acc[0][nt], 0, 0, 0);
            acc[1][nt] = __builtin_amdgcn_mfma_f32_16x16x32_bf16(a1, bf, acc[1][nt], 0, 0, 0);
        }
    }

    // epilogue: D row(t) = g*4 + r (+16*mt), col(c) = m (+16*nt +64*wvid)
    float* outB = outX + (size_t)b*T*NC + (size_t)(wvid*64 + m);
#pragma unroll
    for (int mt = 0; mt < 2; ++mt) {
#pragma unroll
        for (int r = 0; r < 4; ++r) {
            int tt = t0 + mt*16 + g*4 + r;
            if (tt < T) {
#pragma unroll
                for (int nt = 0; nt < 4; ++nt)
                    outB[(size_t)tt*NC + nt*16] = acc[mt][nt][r];
            }
        }
    }
}

// ---------------------------------------------------------------------------
extern "C" void kernel_launch(void* const* d_in, const int* in_sizes, int n_in,
                              void* d_out, int out_size, void* d_ws, size_t ws_size,
                              hipStream_t stream)
{
    const float* x   = (const float*)d_in[0];
    const float* df  = (const float*)d_in[1];
    const float* en  = (const float*)d_in[2];
    const float* pi  = (const float*)d_in[3];
    const float* Wd  = (const float*)d_in[4];
    const float* bd  = (const float*)d_in[5];
    const float* We  = (const float*)d_in[6];
    const float* be  = (const float*)d_in[7];
    const float* Wp  = (const float*)d_in[8];
    const float* bp  = (const float*)d_in[9];
    const float* Wpr = (const float*)d_in[10];
    const float* bpr = (const float*)d_in[11];
    const int*   di  = (const int*)d_in[12];
    const int*   il  = (const int*)d_in[13];

    int T = out_size / (NB * (NC + NL));   // out = B*T*C + B*L*T

    float* outX = (float*)d_out;
    float* outW = outX + (size_t)NB * T * NC;

    float* rdp   = (float*)d_ws;                       // B*L
    float* meanp = rdp   + NB*NL;
    float* invrp = meanp + NB*NL;
    float* coefp = invrp + NB*NL;
    float* dinvp = coefp + NB*NL;                      // B*T  (NB*T % 4 == 0)
    unsigned short* xcT = (unsigned short*)(dinvp + (size_t)NB*T);  // B*16*256*32

    hipLaunchKernelGGL(k_xct, dim3(16, NB), dim3(256), 0, stream,
                       x, en, pi, We, be, Wp, bp, xcT);
    hipLaunchKernelGGL(k_rdx, dim3(NB*NL/4), dim3(256), 0, stream,
                       x, Wpr, rdp);
    hipLaunchKernelGGL(k_ranges, dim3(NB), dim3(512), 0, stream,
                       df, en, pi, di, il, Wd, bd, We, be, Wp, bp, Wpr, bpr,
                       rdp, meanp, invrp, coefp);
    hipLaunchKernelGGL(k_denom, dim3((T+63)/64, NB), dim3(256), 0, stream,
                       meanp, invrp, coefp, dinvp, T);
    hipLaunchKernelGGL(k_weights, dim3(16, NB), dim3(256), 0, stream,
                       meanp, invrp, coefp, dinvp, outW, T);
    hipLaunchKernelGGL(k_gemm, dim3((T+31)/32, NB), dim3(256), 0, stream,
                       xcT, meanp, invrp, coefp, dinvp, outX, T);
}